// Round 1
// baseline (76.126 us; speedup 1.0000x reference)
//
#include <hip/hip_runtime.h>
#include <math.h>

// yoloHeadv3: X (B,255,52,52) f32  ->  out (B, 3*52*52, 85) f32
// B=64, A=3 anchors, C=80 classes, G=52, ratio = 416/52 = 8.
//
// out[b, a*G*G + i*G + j, k]:
//   k=0: (sigmoid(X[b,a*85+0,i,j]) + j) * 8
//   k=1: (sigmoid(X[b,a*85+1,i,j]) + i) * 8
//   k=2: min(exp(X[b,a*85+2,i,j]), 1000) * ANCHOR_X[a]   (scale/8*8 folds exactly)
//   k=3: min(exp(X[b,a*85+3,i,j]), 1000) * ANCHOR_Y[a]
//   k=4: sigmoid(X[b,a*85+4,i,j])
//   k>=5: X[b,a*85+k,i,j]
//
// Memory-bound transpose (85 x 2704 -> 2704 x 85 per (b,a)) via LDS tile.

constexpr int G   = 52;
constexpr int GG  = G * G;          // 2704
constexpr int NA  = 3;
constexpr int NC  = 85;             // channels per anchor
constexpr int TILE = 64;            // ij positions per block
constexpr int NT  = (GG + TILE - 1) / TILE;  // 43 (last tile has 16)
constexpr float RATIO = 8.0f;

__device__ __forceinline__ float sigmoidf_(float v) {
    return 1.0f / (1.0f + expf(-v));
}

__global__ __launch_bounds__(256)
void yolo_head_kernel(const float* __restrict__ X, float* __restrict__ out) {
    // +1 pad: transposed LDS read has bank-stride 65 % 32 == 1 -> conflict-free
    __shared__ float lds[NC][TILE + 1];

    const int bid  = blockIdx.x;
    const int tile = bid % NT;
    const int ba   = bid / NT;
    const int a    = ba % NA;
    const int b    = ba / NA;

    const int ij0 = tile * TILE;
    int n = GG - ij0; if (n > TILE) n = TILE;   // 64, or 16 on the last tile
    const int shift = (n == TILE) ? 4 : 2;      // log2(n/4)
    const int nv    = 1 << shift;               // float4 per channel row
    const int vmask = nv - 1;

    // anchors (wave-uniform a; ternary select -> no scratch array)
    const float ax = (a == 0) ? 116.0f : ((a == 1) ? 156.0f : 373.0f);
    const float ay = (a == 0) ?  90.0f : ((a == 1) ? 198.0f : 326.0f);

    const float4* src = reinterpret_cast<const float4*>(
        X + (((size_t)b * (NA * NC) + (size_t)a * NC) * GG + ij0));
    const int srow = GG / 4;  // 676 float4 per channel

    const int tid = threadIdx.x;

    // ---- load phase: coalesced float4 reads, transform, stage to LDS ----
    const int total = NC * nv;  // 1360 or 340
    for (int idx = tid; idx < total; idx += 256) {
        const int c  = idx >> shift;       // channel k (wave-uniform for full tiles)
        const int v4 = idx & vmask;
        float4 val = src[(size_t)c * srow + v4];
        float vv[4] = {val.x, val.y, val.z, val.w};
        const int ijbase = ij0 + (v4 << 2);
        #pragma unroll
        for (int m = 0; m < 4; ++m) {
            float v = vv[m];
            float r;
            if (c == 0) {
                const int j = (ijbase + m) % G;
                r = (sigmoidf_(v) + (float)j) * RATIO;
            } else if (c == 1) {
                const int i = (ijbase + m) / G;
                r = (sigmoidf_(v) + (float)i) * RATIO;
            } else if (c == 2) {
                r = fminf(expf(v), 1000.0f) * ax;
            } else if (c == 3) {
                r = fminf(expf(v), 1000.0f) * ay;
            } else if (c == 4) {
                r = sigmoidf_(v);
            } else {
                r = v;
            }
            lds[c][(v4 << 2) + m] = r;
        }
    }

    __syncthreads();

    // ---- store phase: contiguous float4 writes of 85-float output rows ----
    float* dst = out + ((size_t)b * NA * GG + (size_t)a * GG + ij0) * NC;
    const int totw = (n * NC) >> 2;   // 1360 or 340 float4
    for (int idx = tid; idx < totw; idx += 256) {
        const int f  = idx << 2;
        int ij = f / NC;              // magic-mul, NC=85 const
        int k  = f - ij * NC;
        float t[4];
        #pragma unroll
        for (int m = 0; m < 4; ++m) {
            t[m] = lds[k][ij];
            ++k;
            if (k == NC) { k = 0; ++ij; }
        }
        float4 o; o.x = t[0]; o.y = t[1]; o.z = t[2]; o.w = t[3];
        reinterpret_cast<float4*>(dst)[idx] = o;
    }
}

extern "C" void kernel_launch(void* const* d_in, const int* in_sizes, int n_in,
                              void* d_out, int out_size, void* d_ws, size_t ws_size,
                              hipStream_t stream) {
    const float* X = (const float*)d_in[0];
    float* out = (float*)d_out;
    const int B = in_sizes[0] / (NA * NC * GG);   // 64
    dim3 grid((unsigned)(B * NA * NT));
    yolo_head_kernel<<<grid, dim3(256), 0, stream>>>(X, out);
}

// Round 2
// 75.923 us; speedup vs baseline: 1.0027x; 1.0027x over previous
//
#include <hip/hip_runtime.h>
#include <math.h>

// yoloHeadv3: X (B,255,52,52) f32  ->  out (B, 3*52*52, 85) f32
// B=64, A=3 anchors, C=80 classes, G=52, ratio = 416/52 = 8.
//
// Memory-bound transpose (85 x 2704 -> 2704 x 85 per (b,a)) via LDS tile.
// Round 2: store phase scalarized — lane-stride across LDS rows is 65 words
// (bank stride 1, conflict-free) instead of 4 rows = 260 words (8-way conflict).

constexpr int G   = 52;
constexpr int GG  = G * G;          // 2704
constexpr int NA  = 3;
constexpr int NC  = 85;             // channels per anchor
constexpr int TILE = 64;            // ij positions per block
constexpr int NT  = (GG + TILE - 1) / TILE;  // 43 (last tile has 16)
constexpr float RATIO = 8.0f;

__device__ __forceinline__ float sigmoidf_(float v) {
    return 1.0f / (1.0f + expf(-v));
}

__global__ __launch_bounds__(256)
void yolo_head_kernel(const float* __restrict__ X, float* __restrict__ out) {
    // row length 65: store-phase lane stride = 65 words -> bank stride 1 (free);
    // load-phase write banks = (c + 4*v4 + m) mod 32 -> exact 2-way (free).
    __shared__ float lds[NC][TILE + 1];

    const int bid  = blockIdx.x;
    const int tile = bid % NT;
    const int ba   = bid / NT;
    const int a    = ba % NA;
    const int b    = ba / NA;

    const int ij0 = tile * TILE;
    int n = GG - ij0; if (n > TILE) n = TILE;   // 64, or 16 on the last tile
    const int shift = (n == TILE) ? 4 : 2;      // log2(n/4)
    const int nv    = 1 << shift;               // float4 per channel row
    const int vmask = nv - 1;

    // anchors (wave-uniform a; ternary select -> no scratch array)
    const float ax = (a == 0) ? 116.0f : ((a == 1) ? 156.0f : 373.0f);
    const float ay = (a == 0) ?  90.0f : ((a == 1) ? 198.0f : 326.0f);

    const float4* src = reinterpret_cast<const float4*>(
        X + (((size_t)b * (NA * NC) + (size_t)a * NC) * GG + ij0));
    const int srow = GG / 4;  // 676 float4 per channel

    const int tid = threadIdx.x;

    // ---- load phase: coalesced float4 reads, transform, stage to LDS ----
    const int total = NC * nv;  // 1360 or 340
    for (int idx = tid; idx < total; idx += 256) {
        const int c  = idx >> shift;       // channel k
        const int v4 = idx & vmask;
        float4 val = src[(size_t)c * srow + v4];
        float vv[4] = {val.x, val.y, val.z, val.w};
        const int ijbase = ij0 + (v4 << 2);
        #pragma unroll
        for (int m = 0; m < 4; ++m) {
            float v = vv[m];
            float r;
            if (c == 0) {
                const int j = (ijbase + m) % G;
                r = (sigmoidf_(v) + (float)j) * RATIO;
            } else if (c == 1) {
                const int i = (ijbase + m) / G;
                r = (sigmoidf_(v) + (float)i) * RATIO;
            } else if (c == 2) {
                r = fminf(expf(v), 1000.0f) * ax;
            } else if (c == 3) {
                r = fminf(expf(v), 1000.0f) * ay;
            } else if (c == 4) {
                r = sigmoidf_(v);
            } else {
                r = v;
            }
            lds[c][(v4 << 2) + m] = r;
        }
    }

    __syncthreads();

    // ---- store phase: scalar, conflict-free LDS reads + coalesced dword stores ----
    float* dst = out + ((size_t)b * NA * GG + (size_t)a * GG + ij0) * NC;
    const int totE = n * NC;          // 5440 or 1360 floats
    for (int idx = tid; idx < totE; idx += 256) {
        const int ij = idx / NC;      // magic-mul (NC=85 const)
        const int k  = idx - ij * NC;
        dst[idx] = lds[k][ij];        // addr = k*65 + ij: lane stride 65 -> bank stride 1
    }
}

extern "C" void kernel_launch(void* const* d_in, const int* in_sizes, int n_in,
                              void* d_out, int out_size, void* d_ws, size_t ws_size,
                              hipStream_t stream) {
    const float* X = (const float*)d_in[0];
    float* out = (float*)d_out;
    const int B = in_sizes[0] / (NA * NC * GG);   // 64
    dim3 grid((unsigned)(B * NA * NT));
    yolo_head_kernel<<<grid, dim3(256), 0, stream>>>(X, out);
}

// Round 3
// 68.533 us; speedup vs baseline: 1.1108x; 1.1078x over previous
//
#include <hip/hip_runtime.h>
#include <math.h>

// yoloHeadv3: X (B,255,52,52) f32  ->  out (B, 3*52*52, 85) f32
// B=64, A=3 anchors, C=80 classes, G=52, ratio = 416/52 = 8.
//
// Round 3: flat LDS layout in EXACT output order: lds[ij_local*85 + k].
//  - load phase : ds_write_b32 at stride-85 words -> 85 coprime 32 banks
//                 -> exactly 2 lanes/bank (free, m136)
//  - store phase: pure linear LDS->global copy, ds_read_b128 +
//                 global_store_dwordx4, zero address math (no div-by-85)
// Both phases unrolled to 6 fixed iterations for full tiles so the 6
// independent global loads issue together (latency hiding).

constexpr int G    = 52;
constexpr int GG   = G * G;          // 2704
constexpr int NA   = 3;
constexpr int NC   = 85;             // channels per anchor
constexpr int TILE = 64;             // ij positions per block
constexpr int NT   = (GG + TILE - 1) / TILE;  // 43 (last tile has 16)
constexpr float RATIO = 8.0f;

__device__ __forceinline__ float sigmoidf_(float v) {
    return 1.0f / (1.0f + expf(-v));
}

__device__ __forceinline__ float transform_(float v, int c, int ij,
                                            float ax, float ay) {
    // c >= 5 (classes) is the common, wave-uniform fast path
    if (c >= 5) return v;
    if (c == 0) return (sigmoidf_(v) + (float)(ij % G)) * RATIO;
    if (c == 1) return (sigmoidf_(v) + (float)(ij / G)) * RATIO;
    if (c == 2) return fminf(expf(v), 1000.0f) * ax;
    if (c == 3) return fminf(expf(v), 1000.0f) * ay;
    return sigmoidf_(v);  // c == 4 (conf)
}

__global__ __launch_bounds__(256)
void yolo_head_kernel(const float* __restrict__ X, float* __restrict__ out) {
    __shared__ float lds[NC * TILE];   // 21760 B, flat: word = ij_local*85 + k

    const int bid  = blockIdx.x;
    const int tile = bid % NT;
    const int ba   = bid / NT;
    const int a    = ba % NA;
    const int b    = ba / NA;

    const int ij0 = tile * TILE;
    const bool full = (tile != NT - 1);          // last tile: n = 16
    const int n = full ? TILE : (GG - ij0);

    const float ax = (a == 0) ? 116.0f : ((a == 1) ? 156.0f : 373.0f);
    const float ay = (a == 0) ?  90.0f : ((a == 1) ? 198.0f : 326.0f);

    const float4* src = reinterpret_cast<const float4*>(
        X + (((size_t)b * (NA * NC) + (size_t)a * NC) * GG + ij0));
    const int srow = GG / 4;  // 676 float4 per channel

    const int tid = threadIdx.x;

    // ---- load phase: coalesced float4 reads, transform, scatter to LDS ----
    if (full) {
        // nv = 16 float4 per channel row; total = 85*16 = 1360 items
        #pragma unroll
        for (int it = 0; it < 6; ++it) {
            const int idx = tid + it * 256;
            if (it < 5 || idx < NC * 16) {
                const int c  = idx >> 4;
                const int v4 = idx & 15;
                float4 val = src[(size_t)c * srow + v4];
                float vv[4] = {val.x, val.y, val.z, val.w};
                const int ijl = v4 << 2;
                #pragma unroll
                for (int m = 0; m < 4; ++m) {
                    lds[(ijl + m) * NC + c] =
                        transform_(vv[m], c, ij0 + ijl + m, ax, ay);
                }
            }
        }
    } else {
        // nv = 4; total = 85*4 = 340 items
        #pragma unroll
        for (int it = 0; it < 2; ++it) {
            const int idx = tid + it * 256;
            if (it < 1 || idx < NC * 4) {
                const int c  = idx >> 2;
                const int v4 = idx & 3;
                float4 val = src[(size_t)c * srow + v4];
                float vv[4] = {val.x, val.y, val.z, val.w};
                const int ijl = v4 << 2;
                #pragma unroll
                for (int m = 0; m < 4; ++m) {
                    lds[(ijl + m) * NC + c] =
                        transform_(vv[m], c, ij0 + ijl + m, ax, ay);
                }
            }
        }
    }

    __syncthreads();

    // ---- store phase: linear LDS -> global copy, b128 reads, x4 stores ----
    float4* dst4 = reinterpret_cast<float4*>(
        out + ((size_t)b * NA * GG + (size_t)a * GG + ij0) * NC);
    const float4* lds4 = reinterpret_cast<const float4*>(lds);

    if (full) {
        // 64*85/4 = 1360 float4
        #pragma unroll
        for (int it = 0; it < 6; ++it) {
            const int idx = tid + it * 256;
            if (it < 5 || idx < (TILE * NC) / 4) {
                dst4[idx] = lds4[idx];
            }
        }
    } else {
        // 16*85/4 = 340 float4
        #pragma unroll
        for (int it = 0; it < 2; ++it) {
            const int idx = tid + it * 256;
            if (it < 1 || idx < (16 * NC) / 4) {
                dst4[idx] = lds4[idx];
            }
        }
    }
    (void)n;
}

extern "C" void kernel_launch(void* const* d_in, const int* in_sizes, int n_in,
                              void* d_out, int out_size, void* d_ws, size_t ws_size,
                              hipStream_t stream) {
    const float* X = (const float*)d_in[0];
    float* out = (float*)d_out;
    const int B = in_sizes[0] / (NA * NC * GG);   // 64
    dim3 grid((unsigned)(B * NA * NT));
    yolo_head_kernel<<<grid, dim3(256), 0, stream>>>(X, out);
}

// Round 5
// 64.255 us; speedup vs baseline: 1.1847x; 1.0666x over previous
//
#include <hip/hip_runtime.h>
#include <math.h>

// yoloHeadv3: X (B,255,52,52) f32  ->  out (B, 3*52*52, 85) f32
// B=64, A=3 anchors, C=80 classes, G=52, ratio = 416/52 = 8.
//
// Round 5: nontemporal output stores (fixed: use clang ext_vector_type,
// HIP_vector_type<float,4> is a struct and rejected by the builtin).
// Output is write-once-never-read; nt stores keep it from evicting X
// (176 MB, re-read every timed replay) out of the 256 MB Infinity Cache.
//
// LDS layout (round 3): flat, exact output order lds[ij_local*85 + k].
//  - load phase : ds_write_b32 stride-85 words, 85 coprime 32 -> 2-way (free)
//  - store phase: linear ds_read_b128 + nt global_store_dwordx4, no addr math

constexpr int G    = 52;
constexpr int GG   = G * G;          // 2704
constexpr int NA   = 3;
constexpr int NC   = 85;             // channels per anchor
constexpr int TILE = 64;             // ij positions per block
constexpr int NT   = (GG + TILE - 1) / TILE;  // 43 (last tile has 16)
constexpr float RATIO = 8.0f;

typedef float f32x4 __attribute__((ext_vector_type(4)));

__device__ __forceinline__ float sigmoidf_(float v) {
    return 1.0f / (1.0f + expf(-v));
}

__device__ __forceinline__ float transform_(float v, int c, int ij,
                                            float ax, float ay) {
    // c >= 5 (classes) is the common, wave-uniform fast path
    if (c >= 5) return v;
    if (c == 0) return (sigmoidf_(v) + (float)(ij % G)) * RATIO;
    if (c == 1) return (sigmoidf_(v) + (float)(ij / G)) * RATIO;
    if (c == 2) return fminf(expf(v), 1000.0f) * ax;
    if (c == 3) return fminf(expf(v), 1000.0f) * ay;
    return sigmoidf_(v);  // c == 4 (conf)
}

__global__ __launch_bounds__(256)
void yolo_head_kernel(const float* __restrict__ X, float* __restrict__ out) {
    __shared__ float lds[NC * TILE];   // 21760 B, flat: word = ij_local*85 + k

    const int bid  = blockIdx.x;
    const int tile = bid % NT;
    const int ba   = bid / NT;
    const int a    = ba % NA;
    const int b    = ba / NA;

    const int ij0 = tile * TILE;
    const bool full = (tile != NT - 1);          // last tile: n = 16

    const float ax = (a == 0) ? 116.0f : ((a == 1) ? 156.0f : 373.0f);
    const float ay = (a == 0) ?  90.0f : ((a == 1) ? 198.0f : 326.0f);

    const f32x4* src = reinterpret_cast<const f32x4*>(
        X + (((size_t)b * (NA * NC) + (size_t)a * NC) * GG + ij0));
    const int srow = GG / 4;  // 676 float4 per channel

    const int tid = threadIdx.x;

    // ---- load phase: coalesced float4 reads, transform, scatter to LDS ----
    if (full) {
        // nv = 16 float4 per channel row; total = 85*16 = 1360 items
        #pragma unroll
        for (int it = 0; it < 6; ++it) {
            const int idx = tid + it * 256;
            if (it < 5 || idx < NC * 16) {
                const int c  = idx >> 4;
                const int v4 = idx & 15;
                f32x4 val = src[(size_t)c * srow + v4];
                const int ijl = v4 << 2;
                #pragma unroll
                for (int m = 0; m < 4; ++m) {
                    lds[(ijl + m) * NC + c] =
                        transform_(val[m], c, ij0 + ijl + m, ax, ay);
                }
            }
        }
    } else {
        // nv = 4; total = 85*4 = 340 items
        #pragma unroll
        for (int it = 0; it < 2; ++it) {
            const int idx = tid + it * 256;
            if (it < 1 || idx < NC * 4) {
                const int c  = idx >> 2;
                const int v4 = idx & 3;
                f32x4 val = src[(size_t)c * srow + v4];
                const int ijl = v4 << 2;
                #pragma unroll
                for (int m = 0; m < 4; ++m) {
                    lds[(ijl + m) * NC + c] =
                        transform_(val[m], c, ij0 + ijl + m, ax, ay);
                }
            }
        }
    }

    __syncthreads();

    // ---- store phase: linear LDS -> global copy, nt dwordx4 stores ----
    f32x4* dst4 = reinterpret_cast<f32x4*>(
        out + ((size_t)b * NA * GG + (size_t)a * GG + ij0) * NC);
    const f32x4* lds4 = reinterpret_cast<const f32x4*>(lds);

    if (full) {
        // 64*85/4 = 1360 float4
        #pragma unroll
        for (int it = 0; it < 6; ++it) {
            const int idx = tid + it * 256;
            if (it < 5 || idx < (TILE * NC) / 4) {
                __builtin_nontemporal_store(lds4[idx], &dst4[idx]);
            }
        }
    } else {
        // 16*85/4 = 340 float4
        #pragma unroll
        for (int it = 0; it < 2; ++it) {
            const int idx = tid + it * 256;
            if (it < 1 || idx < (16 * NC) / 4) {
                __builtin_nontemporal_store(lds4[idx], &dst4[idx]);
            }
        }
    }
}

extern "C" void kernel_launch(void* const* d_in, const int* in_sizes, int n_in,
                              void* d_out, int out_size, void* d_ws, size_t ws_size,
                              hipStream_t stream) {
    const float* X = (const float*)d_in[0];
    float* out = (float*)d_out;
    const int B = in_sizes[0] / (NA * NC * GG);   // 64
    dim3 grid((unsigned)(B * NA * NT));
    yolo_head_kernel<<<grid, dim3(256), 0, stream>>>(X, out);
}